// Round 3
// baseline (405.770 us; speedup 1.0000x reference)
//
#include <hip/hip_runtime.h>
#include <hip/hip_bf16.h>

// EquivariantUpdate, round 3.
// prep -> pack_bmat -> k1_gemm (coalesced LDS-staged bm stream) -> k3_atom -> k2_frag.
// K1 rewritten: M-tile 256 x N 160 x K-tile 64, bf16 LDS double-buffer with XOR
// swizzle; bm read fully coalesced (256B segments). K3/K2 unchanged from round 2.

typedef __attribute__((ext_vector_type(8))) short bfrag8;
typedef __attribute__((ext_vector_type(16))) float f32x16;
typedef __attribute__((ext_vector_type(4))) float f32x4v;

#define MFMA32(A, B, C) __builtin_amdgcn_mfma_f32_32x32x16_bf16((A), (B), (C), 0, 0, 0)

__device__ __forceinline__ f32x16 zero16() {
  f32x16 v;
#pragma unroll
  for (int i = 0; i < 16; ++i) v[i] = 0.0f;
  return v;
}

__device__ __forceinline__ unsigned short bf16bits(float x) {
  __hip_bfloat16 b = __float2bfloat16(x);
  unsigned short u;
  __builtin_memcpy(&u, &b, 2);
  return u;
}

__device__ __forceinline__ unsigned pk2(float lo, float hi) {
  return (unsigned)bf16bits(lo) | ((unsigned)bf16bits(hi) << 16);
}

__device__ __forceinline__ bfrag8 ldfrag(const unsigned short* p) {
  return *reinterpret_cast<const bfrag8*>(p);
}

__device__ __forceinline__ bfrag8 frag4(unsigned f0, unsigned f1, unsigned f2, unsigned f3) {
  union { unsigned u[4]; bfrag8 v; } q;
  q.u[0] = f0; q.u[1] = f1; q.u[2] = f2; q.u[3] = f3;
  return q.v;
}

__device__ __forceinline__ float silu_f(float x) { return x / (1.0f + __expf(-x)); }

// ---------------- prep: all conversions/packs/hfp/zero in one launch ----------------
__global__ __launch_bounds__(256) void prep_kernel(
    const float* __restrict__ h_a, const float* __restrict__ bond,
    const float* __restrict__ h_f,
    const float* __restrict__ aW1, const float* __restrict__ ab1,
    const float* __restrict__ aW2,
    const float* __restrict__ fW1, const float* __restrict__ fW2,
    unsigned short* __restrict__ h_bf, unsigned short* __restrict__ bond_bf,
    float* __restrict__ hfp,
    unsigned short* __restrict__ W1aT, unsigned short* __restrict__ W1bT,
    unsigned short* __restrict__ W1cT, unsigned short* __restrict__ W1eT,
    unsigned short* __restrict__ W2T,
    unsigned short* __restrict__ fW1aT, unsigned short* __restrict__ fW2T,
    float* __restrict__ agg,
    int N, int NB, int F) {
  const int t = threadIdx.x;
  int bid = blockIdx.x;
  const int G_A = (N * 16 + 255) >> 8;
  const int G_B = (NB * 16 + 255) >> 8;
  const int G_H = (F + 1) >> 1;

  if (bid < G_A + G_B) {
    // bf16 convert, permuted row layout: dst[row*128 + h*64 + kc*8 + j]
    const float* src = (bid < G_A) ? h_a : bond;
    unsigned short* dst = (bid < G_A) ? h_bf : bond_bf;
    int rows = (bid < G_A) ? N : NB;
    int idx = (bid < G_A ? bid : bid - G_A) * 256 + t;
    if (idx < rows * 16) {
      int row = idx >> 4, g = idx & 15;
      int h = g & 1, kc = g >> 1;
      const f32x4v* s = reinterpret_cast<const f32x4v*>(src + (size_t)row * 128 + g * 8);
      f32x4v v0 = s[0], v1 = s[1];
      unsigned* d = reinterpret_cast<unsigned*>(dst + (size_t)row * 128 + h * 64 + kc * 8);
      d[0] = pk2(v0[0], v0[1]);
      d[1] = pk2(v0[2], v0[3]);
      d[2] = pk2(v1[0], v1[1]);
      d[3] = pk2(v1[2], v1[3]);
    }
    return;
  }
  bid -= G_A + G_B;
  if (bid < G_H) {
    int f = bid * 2 + (t >> 7), n = t & 127;
    if (f < F) {
      float acc = 0.0f;
#pragma unroll 8
      for (int k = 0; k < 128; ++k)
        acc += h_f[(size_t)f * 128 + k] * fW1[(size_t)(128 + k) * 128 + n];
      hfp[(size_t)f * 128 + n] = acc;
    }
    return;
  }
  bid -= G_H;
  if (bid < 6 * 64) {
    int p = bid >> 6;
    int tt = (bid & 63) * 256 + t;
    int j = tt & 7, l = (tt >> 3) & 63, rem = tt >> 9;
    int nt = rem & 3, kc = rem >> 2;
    int k = kc * 16 + ((l >> 5) << 3) + j;
    int n = nt * 32 + (l & 31);
    const float* W;
    unsigned short* D;
    switch (p) {
      case 0: W = aW1;             D = W1aT;  break;
      case 1: W = aW1 + 128 * 128; D = W1bT;  break;
      case 2: W = aW1 + 258 * 128; D = W1cT;  break;
      case 3: W = aW2;             D = W2T;   break;
      case 4: W = fW1;             D = fW1aT; break;
      default: W = fW2;            D = fW2T;  break;
    }
    D[tt] = bf16bits(W[(size_t)k * 128 + n]);
    return;
  }
  bid -= 6 * 64;
  if (bid < 8) {
    int tt = bid * 256 + t;
    if (tt < 4 * 64 * 8) {
      int j = tt & 7, l = (tt >> 3) & 63, nt = (tt >> 9) & 3;
      int k = ((l >> 5) << 3) + j;
      int n = nt * 32 + (l & 31);
      float v = (k == 0) ? aW1[(size_t)256 * 128 + n]
              : (k == 1) ? aW1[(size_t)257 * 128 + n]
              : (k == 2) ? ab1[n] : 0.0f;
      W1eT[tt] = bf16bits(v);
    }
    return;
  }
  bid -= 8;
  {
    int i4 = (bid * 256 + t) * 4;
    if (i4 + 3 < N * 3) {
      *reinterpret_cast<f32x4v*>(agg + i4) = f32x4v{0.f, 0.f, 0.f, 0.f};
    } else {
      for (int c = 0; c < 4; ++c)
        if (i4 + c < N * 3) agg[i4 + c] = 0.0f;
    }
  }
}

// K1's A operand: Bmat^T frags. Bmat[k][n] = n<128 ? hfp[k][n] : (n<131 ? x_f[k][n-128] : 0)
__global__ void pack_bmat_kernel(const float* __restrict__ hfp, const float* __restrict__ x_f,
                                 unsigned short* __restrict__ dst, int total) {
  int t = blockIdx.x * blockDim.x + threadIdx.x;
  if (t >= total) return;
  int j = t & 7, l = (t >> 3) & 63, rem = t >> 9;
  int nt = rem % 5, kc = rem / 5;
  int k = kc * 16 + ((l >> 5) << 3) + j;
  int n = nt * 32 + (l & 31);
  float v;
  if (n < 128) v = hfp[(size_t)k * 128 + n];
  else if (n < 131) v = x_f[(size_t)k * 3 + (n - 128)];
  else v = 0.0f;
  dst[t] = bf16bits(v);
}

// ---------------- K1: coalesced LDS-staged GEMM, streams bm once ----------------
// D[n][m] = sum_k Bmat[k][n] * bm[m][k]. Block: 512 thr (8 waves), M-tile 256,
// K-tile 64. bm tile staged f32->bf16 into XOR-swizzled LDS, double-buffered.
__global__ __launch_bounds__(512, 1) void k1_gemm(
    const float* __restrict__ bm, const unsigned short* __restrict__ bmT,
    float* __restrict__ k1T, int N, int F) {
  __shared__ __align__(16) char lds[2][256 * 128];  // 2 x 32 KB bf16 tiles
  const int t = threadIdx.x;
  const int lane = t & 63;
  const int w = t >> 6;
  const int h = lane >> 5;
  const int ln = lane & 31;
  const int m0 = blockIdx.x * 256;
  const int NT = (F + 63) >> 6;

  f32x16 acc[5];
#pragma unroll
  for (int i = 0; i < 5; ++i) acc[i] = zero16();

  // staging map: chunk c = p*512 + t; row = c>>4 (0..255), ch = c&15 (16B f32 chunk)
  int srow[8], sch[8];
  const float* sptr[8];
#pragma unroll
  for (int p = 0; p < 8; ++p) {
    int c = p * 512 + t;
    srow[p] = c >> 4;
    sch[p] = c & 15;
    int gr = m0 + srow[p];
    if (gr >= N) gr = N - 1;
    sptr[p] = bm + (size_t)gr * F;
  }

  const int myrow = w * 32 + ln;
  const int rsw = (myrow & 7) << 4;

  f32x4v sregs[8];
  // prologue: stage tile 0
#pragma unroll
  for (int p = 0; p < 8; ++p) {
    int gk = sch[p] * 4;
    if (gk > F - 4) gk = F - 4;
    sregs[p] = *reinterpret_cast<const f32x4v*>(sptr[p] + gk);
  }
#pragma unroll
  for (int p = 0; p < 8; ++p) {
    int byte = srow[p] * 128 + ((sch[p] * 8) ^ ((srow[p] & 7) << 4));
    union { unsigned u[2]; unsigned long long ull; } q;
    q.u[0] = pk2(sregs[p][0], sregs[p][1]);
    q.u[1] = pk2(sregs[p][2], sregs[p][3]);
    *reinterpret_cast<unsigned long long*>(&lds[0][byte]) = q.ull;
  }
  __syncthreads();

  int cur = 0;
  for (int kt = 0; kt < NT; ++kt) {
    const bool more = (kt + 1 < NT);
    if (more) {
      // issue next-tile global loads early (latency hides under MFMA)
#pragma unroll
      for (int p = 0; p < 8; ++p) {
        int gk = (kt + 1) * 64 + sch[p] * 4;
        if (gk > F - 4) gk = F - 4;
        sregs[p] = *reinterpret_cast<const f32x4v*>(sptr[p] + gk);
      }
    }
    // compute current tile
    const int kcCount = ((F - kt * 64) >> 4) < 4 ? ((F - kt * 64) >> 4) : 4;
    for (int kc = 0; kc < kcCount; ++kc) {
      bfrag8 b = *reinterpret_cast<const bfrag8*>(
          &lds[cur][myrow * 128 + ((kc * 32 + h * 16) ^ rsw)]);
      const int kcg = kt * 4 + kc;
      const unsigned short* wp = bmT + ((size_t)kcg * 5 * 64 + lane) * 8;
#pragma unroll
      for (int nt = 0; nt < 5; ++nt) acc[nt] = MFMA32(ldfrag(wp + nt * 512), b, acc[nt]);
    }
    if (more) {
#pragma unroll
      for (int p = 0; p < 8; ++p) {
        int byte = srow[p] * 128 + ((sch[p] * 8) ^ ((srow[p] & 7) << 4));
        union { unsigned u[2]; unsigned long long ull; } q;
        q.u[0] = pk2(sregs[p][0], sregs[p][1]);
        q.u[1] = pk2(sregs[p][2], sregs[p][3]);
        *reinterpret_cast<unsigned long long*>(&lds[cur ^ 1][byte]) = q.ull;
      }
    }
    __syncthreads();
    cur ^= 1;
  }

  const int m = m0 + myrow;
  if (m < N) {
#pragma unroll
    for (int nt = 0; nt < 5; ++nt)
#pragma unroll
      for (int r = 0; r < 16; ++r) {
        int n = nt * 32 + (r & 3) + 8 * (r >> 2) + 4 * h;
        if (n < 131) k1T[(size_t)n * N + m] = acc[nt][r];
      }
  }
}

// ---------------- K3: atom MLP over edges + atomic segment sum ----------------
__global__ __launch_bounds__(256) void k3_atom(
    const unsigned short* __restrict__ h_bf, const unsigned short* __restrict__ bond_bf,
    const int* __restrict__ eidx, const int* __restrict__ etype,
    const float* __restrict__ eattr, const float* __restrict__ cda,
    const unsigned short* __restrict__ W1aT, const unsigned short* __restrict__ W1bT,
    const unsigned short* __restrict__ W1cT, const unsigned short* __restrict__ W1eT,
    const unsigned short* __restrict__ W2T,
    const float* __restrict__ ab2, const float* __restrict__ aW3,
    float* __restrict__ agg, int E) {
  const int lane = threadIdx.x & 63;
  const int wid = threadIdx.x >> 6;
  const int h = lane >> 5;
  const int ln = lane & 31;
  const int e = blockIdx.x * 128 + wid * 32 + ln;
  const bool valid = (e < E);
  const int ec = valid ? e : (E - 1);
  const int row = eidx[ec];
  const int col = eidx[(size_t)E + ec];
  const int typ = etype[ec];
  const float e0 = eattr[2 * (size_t)ec];
  const float e1 = eattr[2 * (size_t)ec + 1];

  const unsigned short* hr = h_bf + (size_t)row * 128 + h * 64;
  const unsigned short* hc = h_bf + (size_t)col * 128 + h * 64;
  const unsigned short* bb = bond_bf + (size_t)typ * 128 + h * 64;

  f32x16 acc[4];
#pragma unroll
  for (int q = 0; q < 4; ++q) acc[q] = zero16();

#pragma unroll
  for (int kc = 0; kc < 8; ++kc) {
    bfrag8 b = ldfrag(hr + kc * 8);
    const unsigned short* wp = W1aT + ((size_t)(kc * 4) * 64 + lane) * 8;
#pragma unroll
    for (int nt = 0; nt < 4; ++nt) acc[nt] = MFMA32(ldfrag(wp + nt * 512), b, acc[nt]);
  }
#pragma unroll
  for (int kc = 0; kc < 8; ++kc) {
    bfrag8 b = ldfrag(hc + kc * 8);
    const unsigned short* wp = W1bT + ((size_t)(kc * 4) * 64 + lane) * 8;
#pragma unroll
    for (int nt = 0; nt < 4; ++nt) acc[nt] = MFMA32(ldfrag(wp + nt * 512), b, acc[nt]);
  }
#pragma unroll
  for (int kc = 0; kc < 8; ++kc) {
    bfrag8 b = ldfrag(bb + kc * 8);
    const unsigned short* wp = W1cT + ((size_t)(kc * 4) * 64 + lane) * 8;
#pragma unroll
    for (int nt = 0; nt < 4; ++nt) acc[nt] = MFMA32(ldfrag(wp + nt * 512), b, acc[nt]);
  }
  {
    unsigned u0 = h ? 0u : pk2(e0, e1);
    unsigned u1 = h ? 0u : 0x00003F80u;  // bf16(1.0) at k=2 -> carries ab1
    bfrag8 b = frag4(u0, u1, 0u, 0u);
    const unsigned short* wp = W1eT + (size_t)lane * 8;
#pragma unroll
    for (int nt = 0; nt < 4; ++nt) acc[nt] = MFMA32(ldfrag(wp + nt * 512), b, acc[nt]);
  }

  unsigned w[32];
#pragma unroll
  for (int nt = 0; nt < 4; ++nt)
#pragma unroll
    for (int p = 0; p < 8; ++p)
      w[nt * 8 + p] = pk2(silu_f(acc[nt][2 * p]), silu_f(acc[nt][2 * p + 1]));

#pragma unroll
  for (int q = 0; q < 4; ++q) acc[q] = zero16();
#pragma unroll
  for (int kc = 0; kc < 8; ++kc) {
    const int base = (kc >> 1) * 8 + (kc & 1) * 4;
    unsigned a0 = w[base + 0], a1 = w[base + 1], a2 = w[base + 2], a3 = w[base + 3];
    unsigned s0 = (unsigned)__shfl_xor((int)a0, 32);
    unsigned s1 = (unsigned)__shfl_xor((int)a1, 32);
    unsigned s2 = (unsigned)__shfl_xor((int)a2, 32);
    unsigned s3 = (unsigned)__shfl_xor((int)a3, 32);
    bfrag8 b = frag4(h ? s2 : a0, h ? s3 : a1, h ? a2 : s0, h ? a3 : s1);
    const unsigned short* wp = W2T + ((size_t)(kc * 4) * 64 + lane) * 8;
#pragma unroll
    for (int nt = 0; nt < 4; ++nt) acc[nt] = MFMA32(ldfrag(wp + nt * 512), b, acc[nt]);
  }

  float part = 0.0f;
#pragma unroll
  for (int nt = 0; nt < 4; ++nt)
#pragma unroll
    for (int r = 0; r < 16; ++r) {
      int n = nt * 32 + (r & 3) + 8 * (r >> 2) + 4 * h;
      part += silu_f(acc[nt][r] + ab2[n]) * aW3[n];
    }
  float mv = part + __shfl_xor(part, 32);

  if (valid) {
    float tt = tanhf(mv) * 0.1f;
    if (h == 0) {
      atomicAdd(agg + 3 * (size_t)row + 0, cda[3 * (size_t)ec + 0] * tt);
      atomicAdd(agg + 3 * (size_t)row + 1, cda[3 * (size_t)ec + 1] * tt);
    } else {
      atomicAdd(agg + 3 * (size_t)row + 2, cda[3 * (size_t)ec + 2] * tt);
    }
  }
}

// ---------------- K2: fragment MLP + compose output ----------------
__global__ __launch_bounds__(256) void k2_frag(
    const float* __restrict__ x_a, const unsigned short* __restrict__ h_bf,
    const float* __restrict__ k1T, const float* __restrict__ agg,
    const unsigned short* __restrict__ fW1aT, const unsigned short* __restrict__ fW2T,
    const float* __restrict__ fW1, const float* __restrict__ fb1,
    const float* __restrict__ fb2, const float* __restrict__ fW3,
    float* __restrict__ out, int N) {
  const int lane = threadIdx.x & 63;
  const int wid = threadIdx.x >> 6;
  const int h = lane >> 5;
  const int ln = lane & 31;
  const int i = blockIdx.x * 128 + wid * 32 + ln;
  const bool valid = (i < N);
  const int ic = valid ? i : (N - 1);

  float cd[3];
  float radial = 0.0f;
#pragma unroll
  for (int c = 0; c < 3; ++c) {
    float v = x_a[3 * (size_t)ic + c] - k1T[(size_t)(128 + c) * N + ic];
    cd[c] = v;
    radial += v * v;
  }

  f32x16 acc[4];
#pragma unroll
  for (int q = 0; q < 4; ++q) acc[q] = zero16();
  const unsigned short* hp = h_bf + (size_t)ic * 128 + h * 64;
#pragma unroll
  for (int kc = 0; kc < 8; ++kc) {
    bfrag8 b = ldfrag(hp + kc * 8);
    const unsigned short* wp = fW1aT + ((size_t)(kc * 4) * 64 + lane) * 8;
#pragma unroll
    for (int nt = 0; nt < 4; ++nt) acc[nt] = MFMA32(ldfrag(wp + nt * 512), b, acc[nt]);
  }

  unsigned w[32];
#pragma unroll
  for (int nt = 0; nt < 4; ++nt)
#pragma unroll
    for (int p = 0; p < 8; ++p) {
      const int r0 = 2 * p;
      const int n0 = nt * 32 + (r0 & 3) + 8 * (r0 >> 2) + 4 * h;
      const int n1 = n0 + 1;
      float q0 = acc[nt][r0] + k1T[(size_t)n0 * N + ic]
               + radial * (fW1[(size_t)256 * 128 + n0] + fW1[(size_t)257 * 128 + n0]) + fb1[n0];
      float q1 = acc[nt][r0 + 1] + k1T[(size_t)n1 * N + ic]
               + radial * (fW1[(size_t)256 * 128 + n1] + fW1[(size_t)257 * 128 + n1]) + fb1[n1];
      w[nt * 8 + p] = pk2(silu_f(q0), silu_f(q1));
    }

#pragma unroll
  for (int q = 0; q < 4; ++q) acc[q] = zero16();
#pragma unroll
  for (int kc = 0; kc < 8; ++kc) {
    const int base = (kc >> 1) * 8 + (kc & 1) * 4;
    unsigned a0 = w[base + 0], a1 = w[base + 1], a2 = w[base + 2], a3 = w[base + 3];
    unsigned s0 = (unsigned)__shfl_xor((int)a0, 32);
    unsigned s1 = (unsigned)__shfl_xor((int)a1, 32);
    unsigned s2 = (unsigned)__shfl_xor((int)a2, 32);
    unsigned s3 = (unsigned)__shfl_xor((int)a3, 32);
    bfrag8 b = frag4(h ? s2 : a0, h ? s3 : a1, h ? a2 : s0, h ? a3 : s1);
    const unsigned short* wp = fW2T + ((size_t)(kc * 4) * 64 + lane) * 8;
#pragma unroll
    for (int nt = 0; nt < 4; ++nt) acc[nt] = MFMA32(ldfrag(wp + nt * 512), b, acc[nt]);
  }

  float part = 0.0f;
#pragma unroll
  for (int nt = 0; nt < 4; ++nt)
#pragma unroll
    for (int r = 0; r < 16; ++r) {
      int n = nt * 32 + (r & 3) + 8 * (r >> 2) + 4 * h;
      part += silu_f(acc[nt][r] + fb2[n]) * fW3[n];
    }
  float mv = part + __shfl_xor(part, 32);

  if (valid && h == 0) {
    float nrm = sqrtf(radial + 1e-8f);
    float s = tanhf(mv) * 10.0f / (nrm + 1.0f);
#pragma unroll
    for (int c = 0; c < 3; ++c)
      out[3 * (size_t)i + c] = x_a[3 * (size_t)i + c] + cd[c] * s + agg[3 * (size_t)i + c];
  }
}

// ---------------- launch ----------------

extern "C" void kernel_launch(void* const* d_in, const int* in_sizes, int n_in,
                              void* d_out, int out_size, void* d_ws, size_t ws_size,
                              hipStream_t stream) {
  const float* h_a    = (const float*)d_in[0];
  const float* x_a    = (const float*)d_in[1];
  const int*   e_idx  = (const int*)d_in[2];
  const int*   e_type = (const int*)d_in[3];
  const float* e_attr = (const float*)d_in[4];
  const float* cda    = (const float*)d_in[5];
  const float* h_f    = (const float*)d_in[6];
  const float* x_f    = (const float*)d_in[7];
  const float* bm     = (const float*)d_in[8];
  const float* bond   = (const float*)d_in[9];
  const float* aW1    = (const float*)d_in[10];
  const float* ab1    = (const float*)d_in[11];
  const float* aW2    = (const float*)d_in[12];
  const float* ab2    = (const float*)d_in[13];
  const float* aW3    = (const float*)d_in[14];
  const float* fW1    = (const float*)d_in[15];
  const float* fb1    = (const float*)d_in[16];
  const float* fW2    = (const float*)d_in[17];
  const float* fb2    = (const float*)d_in[18];
  const float* fW3    = (const float*)d_in[19];
  float* out = (float*)d_out;

  const int N  = in_sizes[0] / 128;
  const int E  = in_sizes[2] / 2;
  const int F  = in_sizes[6] / 128;
  const int NB = in_sizes[9] / 128;
  const int KC = F / 16;

  char* wsp = (char*)d_ws;
  size_t off = 0;
  auto alloc = [&](size_t bytes) -> char* {
    char* p = wsp + off;
    off += (bytes + 255) & ~(size_t)255;
    return p;
  };
  unsigned short* h_bf    = (unsigned short*)alloc((size_t)N * 128 * 2);
  unsigned short* bond_bf = (unsigned short*)alloc((size_t)NB * 128 * 2);
  float*          hfp     = (float*)alloc((size_t)F * 128 * 4);
  unsigned short* bmT     = (unsigned short*)alloc((size_t)KC * 5 * 64 * 8 * 2);
  unsigned short* W1aT    = (unsigned short*)alloc(8 * 4 * 64 * 8 * 2);
  unsigned short* W1bT    = (unsigned short*)alloc(8 * 4 * 64 * 8 * 2);
  unsigned short* W1cT    = (unsigned short*)alloc(8 * 4 * 64 * 8 * 2);
  unsigned short* W2T     = (unsigned short*)alloc(8 * 4 * 64 * 8 * 2);
  unsigned short* fW1aT   = (unsigned short*)alloc(8 * 4 * 64 * 8 * 2);
  unsigned short* fW2T    = (unsigned short*)alloc(8 * 4 * 64 * 8 * 2);
  unsigned short* W1eT    = (unsigned short*)alloc(1 * 4 * 64 * 8 * 2);
  float*          k1T     = (float*)alloc((size_t)131 * N * 4);
  float*          agg     = (float*)alloc((size_t)N * 3 * 4);

  const int G_A = (N * 16 + 255) >> 8;
  const int G_B = (NB * 16 + 255) >> 8;
  const int G_H = (F + 1) >> 1;
  const int G_P = 6 * 64;
  const int G_E2 = 8;
  const int G_Z = (N * 3 + 1023) >> 10;
  prep_kernel<<<G_A + G_B + G_H + G_P + G_E2 + G_Z, 256, 0, stream>>>(
      h_a, bond, h_f, aW1, ab1, aW2, fW1, fW2,
      h_bf, bond_bf, hfp, W1aT, W1bT, W1cT, W1eT, W2T, fW1aT, fW2T, agg,
      N, NB, F);

  {
    int total = KC * 5 * 64 * 8;
    pack_bmat_kernel<<<(total + 255) / 256, 256, 0, stream>>>(hfp, x_f, bmT, total);
  }

  k1_gemm<<<(N + 255) / 256, 512, 0, stream>>>(bm, bmT, k1T, N, F);

  k3_atom<<<(E + 127) / 128, 256, 0, stream>>>(h_bf, bond_bf, e_idx, e_type, e_attr, cda,
                                               W1aT, W1bT, W1cT, W1eT, W2T, ab2, aW3, agg, E);

  k2_frag<<<(N + 127) / 128, 256, 0, stream>>>(x_a, h_bf, k1T, agg, fW1aT, fW2T,
                                               fW1, fb1, fb2, fW3, out, N);
}

// Round 4
// 358.466 us; speedup vs baseline: 1.1320x; 1.1320x over previous
//
#include <hip/hip_runtime.h>
#include <hip/hip_bf16.h>

// EquivariantUpdate, round 4.
// prep -> pack_bmat -> fused(K1|K3) -> k2_frag.
// K1: M-tile 128, K-tile 64, 256 thr, 2x16KB LDS double-buffer (3 blocks/CU
// resident -> cross-block latency hiding). K3 blocks co-scheduled in the same
// launch so MFMA/L2 work overlaps K1's HBM streaming.

typedef __attribute__((ext_vector_type(8))) short bfrag8;
typedef __attribute__((ext_vector_type(16))) float f32x16;
typedef __attribute__((ext_vector_type(4))) float f32x4v;

#define MFMA32(A, B, C) __builtin_amdgcn_mfma_f32_32x32x16_bf16((A), (B), (C), 0, 0, 0)

__device__ __forceinline__ f32x16 zero16() {
  f32x16 v;
#pragma unroll
  for (int i = 0; i < 16; ++i) v[i] = 0.0f;
  return v;
}

__device__ __forceinline__ unsigned short bf16bits(float x) {
  __hip_bfloat16 b = __float2bfloat16(x);
  unsigned short u;
  __builtin_memcpy(&u, &b, 2);
  return u;
}

__device__ __forceinline__ unsigned pk2(float lo, float hi) {
  return (unsigned)bf16bits(lo) | ((unsigned)bf16bits(hi) << 16);
}

__device__ __forceinline__ bfrag8 ldfrag(const unsigned short* p) {
  return *reinterpret_cast<const bfrag8*>(p);
}

__device__ __forceinline__ bfrag8 frag4(unsigned f0, unsigned f1, unsigned f2, unsigned f3) {
  union { unsigned u[4]; bfrag8 v; } q;
  q.u[0] = f0; q.u[1] = f1; q.u[2] = f2; q.u[3] = f3;
  return q.v;
}

__device__ __forceinline__ float silu_f(float x) { return x / (1.0f + __expf(-x)); }

// ---------------- prep: all conversions/packs/hfp/zero in one launch ----------------
__global__ __launch_bounds__(256) void prep_kernel(
    const float* __restrict__ h_a, const float* __restrict__ bond,
    const float* __restrict__ h_f,
    const float* __restrict__ aW1, const float* __restrict__ ab1,
    const float* __restrict__ aW2,
    const float* __restrict__ fW1, const float* __restrict__ fW2,
    unsigned short* __restrict__ h_bf, unsigned short* __restrict__ bond_bf,
    float* __restrict__ hfp,
    unsigned short* __restrict__ W1aT, unsigned short* __restrict__ W1bT,
    unsigned short* __restrict__ W1cT, unsigned short* __restrict__ W1eT,
    unsigned short* __restrict__ W2T,
    unsigned short* __restrict__ fW1aT, unsigned short* __restrict__ fW2T,
    float* __restrict__ agg,
    int N, int NB, int F) {
  const int t = threadIdx.x;
  int bid = blockIdx.x;
  const int G_A = (N * 16 + 255) >> 8;
  const int G_B = (NB * 16 + 255) >> 8;
  const int G_H = (F + 1) >> 1;

  if (bid < G_A + G_B) {
    // bf16 convert, permuted row layout: dst[row*128 + h*64 + kc*8 + j]
    const float* src = (bid < G_A) ? h_a : bond;
    unsigned short* dst = (bid < G_A) ? h_bf : bond_bf;
    int rows = (bid < G_A) ? N : NB;
    int idx = (bid < G_A ? bid : bid - G_A) * 256 + t;
    if (idx < rows * 16) {
      int row = idx >> 4, g = idx & 15;
      int h = g & 1, kc = g >> 1;
      const f32x4v* s = reinterpret_cast<const f32x4v*>(src + (size_t)row * 128 + g * 8);
      f32x4v v0 = s[0], v1 = s[1];
      unsigned* d = reinterpret_cast<unsigned*>(dst + (size_t)row * 128 + h * 64 + kc * 8);
      d[0] = pk2(v0[0], v0[1]);
      d[1] = pk2(v0[2], v0[3]);
      d[2] = pk2(v1[0], v1[1]);
      d[3] = pk2(v1[2], v1[3]);
    }
    return;
  }
  bid -= G_A + G_B;
  if (bid < G_H) {
    int f = bid * 2 + (t >> 7), n = t & 127;
    if (f < F) {
      float acc = 0.0f;
#pragma unroll 8
      for (int k = 0; k < 128; ++k)
        acc += h_f[(size_t)f * 128 + k] * fW1[(size_t)(128 + k) * 128 + n];
      hfp[(size_t)f * 128 + n] = acc;
    }
    return;
  }
  bid -= G_H;
  if (bid < 6 * 64) {
    int p = bid >> 6;
    int tt = (bid & 63) * 256 + t;
    int j = tt & 7, l = (tt >> 3) & 63, rem = tt >> 9;
    int nt = rem & 3, kc = rem >> 2;
    int k = kc * 16 + ((l >> 5) << 3) + j;
    int n = nt * 32 + (l & 31);
    const float* W;
    unsigned short* D;
    switch (p) {
      case 0: W = aW1;             D = W1aT;  break;
      case 1: W = aW1 + 128 * 128; D = W1bT;  break;
      case 2: W = aW1 + 258 * 128; D = W1cT;  break;
      case 3: W = aW2;             D = W2T;   break;
      case 4: W = fW1;             D = fW1aT; break;
      default: W = fW2;            D = fW2T;  break;
    }
    D[tt] = bf16bits(W[(size_t)k * 128 + n]);
    return;
  }
  bid -= 6 * 64;
  if (bid < 8) {
    int tt = bid * 256 + t;
    if (tt < 4 * 64 * 8) {
      int j = tt & 7, l = (tt >> 3) & 63, nt = (tt >> 9) & 3;
      int k = ((l >> 5) << 3) + j;
      int n = nt * 32 + (l & 31);
      float v = (k == 0) ? aW1[(size_t)256 * 128 + n]
              : (k == 1) ? aW1[(size_t)257 * 128 + n]
              : (k == 2) ? ab1[n] : 0.0f;
      W1eT[tt] = bf16bits(v);
    }
    return;
  }
  bid -= 8;
  {
    int i4 = (bid * 256 + t) * 4;
    if (i4 + 3 < N * 3) {
      *reinterpret_cast<f32x4v*>(agg + i4) = f32x4v{0.f, 0.f, 0.f, 0.f};
    } else {
      for (int c = 0; c < 4; ++c)
        if (i4 + c < N * 3) agg[i4 + c] = 0.0f;
    }
  }
}

// K1's A operand: Bmat^T frags. Bmat[k][n] = n<128 ? hfp[k][n] : (n<131 ? x_f[k][n-128] : 0)
__global__ void pack_bmat_kernel(const float* __restrict__ hfp, const float* __restrict__ x_f,
                                 unsigned short* __restrict__ dst, int total) {
  int t = blockIdx.x * blockDim.x + threadIdx.x;
  if (t >= total) return;
  int j = t & 7, l = (t >> 3) & 63, rem = t >> 9;
  int nt = rem % 5, kc = rem / 5;
  int k = kc * 16 + ((l >> 5) << 3) + j;
  int n = nt * 32 + (l & 31);
  float v;
  if (n < 128) v = hfp[(size_t)k * 128 + n];
  else if (n < 131) v = x_f[(size_t)k * 3 + (n - 128)];
  else v = 0.0f;
  dst[t] = bf16bits(v);
}

// ---------------- fused: K1 (M128 LDS-dbuf GEMM) | K3 (edge MLP) ----------------
__global__ __launch_bounds__(256, 2) void fused_k1_k3(
    const float* __restrict__ bm, const unsigned short* __restrict__ bmT,
    float* __restrict__ k1T,
    const unsigned short* __restrict__ h_bf, const unsigned short* __restrict__ bond_bf,
    const int* __restrict__ eidx, const int* __restrict__ etype,
    const float* __restrict__ eattr, const float* __restrict__ cda,
    const unsigned short* __restrict__ W1aT, const unsigned short* __restrict__ W1bT,
    const unsigned short* __restrict__ W1cT, const unsigned short* __restrict__ W1eT,
    const unsigned short* __restrict__ W2T,
    const float* __restrict__ ab2, const float* __restrict__ aW3,
    float* __restrict__ agg,
    int N, int F, int E, int G1) {
  __shared__ __align__(16) char lds[2][128 * 128];  // 2 x 16KB bf16 tiles (k1 only)
  const int lane = threadIdx.x & 63;
  const int w = threadIdx.x >> 6;
  const int h = lane >> 5;
  const int ln = lane & 31;

  if ((int)blockIdx.x < G1) {
    // ---- K1: D[n][m] = sum_k Bmat[k][n] * bm[m][k] ----
    const int t = threadIdx.x;
    const int m0 = blockIdx.x * 128;
    const int NT = (F + 63) >> 6;

    f32x16 acc[5];
#pragma unroll
    for (int i = 0; i < 5; ++i) acc[i] = zero16();

    // staging: 128 rows x 16 chunks (16B f32) = 2048 chunks, 8 per thread
    int srow[8], sch[8];
    const float* sptr[8];
#pragma unroll
    for (int p = 0; p < 8; ++p) {
      int c = p * 256 + t;
      srow[p] = c >> 4;
      sch[p] = c & 15;
      int gr = m0 + srow[p];
      if (gr >= N) gr = N - 1;
      sptr[p] = bm + (size_t)gr * F;
    }

    const int myrow = w * 32 + ln;
    const int rsw = (myrow & 7) << 4;

    f32x4v sregs[8];
#pragma unroll
    for (int p = 0; p < 8; ++p) {
      int gk = sch[p] * 4;
      if (gk > F - 4) gk = F - 4;
      sregs[p] = *reinterpret_cast<const f32x4v*>(sptr[p] + gk);
    }
#pragma unroll
    for (int p = 0; p < 8; ++p) {
      int byte = srow[p] * 128 + ((sch[p] * 8) ^ ((srow[p] & 7) << 4));
      union { unsigned u[2]; unsigned long long ull; } q;
      q.u[0] = pk2(sregs[p][0], sregs[p][1]);
      q.u[1] = pk2(sregs[p][2], sregs[p][3]);
      *reinterpret_cast<unsigned long long*>(&lds[0][byte]) = q.ull;
    }
    __syncthreads();

    int cur = 0;
    for (int kt = 0; kt < NT; ++kt) {
      const bool more = (kt + 1 < NT);
      if (more) {
#pragma unroll
        for (int p = 0; p < 8; ++p) {
          int gk = (kt + 1) * 64 + sch[p] * 4;
          if (gk > F - 4) gk = F - 4;
          sregs[p] = *reinterpret_cast<const f32x4v*>(sptr[p] + gk);
        }
      }
      const int rem = (F - kt * 64) >> 4;
      const int kcN = rem < 4 ? rem : 4;
      if (kcN == 4) {
#pragma unroll
        for (int kc = 0; kc < 4; ++kc) {
          bfrag8 b = *reinterpret_cast<const bfrag8*>(
              &lds[cur][myrow * 128 + ((kc * 32 + h * 16) ^ rsw)]);
          const unsigned short* wp = bmT + ((size_t)(kt * 4 + kc) * 5 * 64 + lane) * 8;
#pragma unroll
          for (int nt = 0; nt < 5; ++nt) acc[nt] = MFMA32(ldfrag(wp + nt * 512), b, acc[nt]);
        }
      } else {
        for (int kc = 0; kc < kcN; ++kc) {
          bfrag8 b = *reinterpret_cast<const bfrag8*>(
              &lds[cur][myrow * 128 + ((kc * 32 + h * 16) ^ rsw)]);
          const unsigned short* wp = bmT + ((size_t)(kt * 4 + kc) * 5 * 64 + lane) * 8;
#pragma unroll
          for (int nt = 0; nt < 5; ++nt) acc[nt] = MFMA32(ldfrag(wp + nt * 512), b, acc[nt]);
        }
      }
      if (more) {
#pragma unroll
        for (int p = 0; p < 8; ++p) {
          int byte = srow[p] * 128 + ((sch[p] * 8) ^ ((srow[p] & 7) << 4));
          union { unsigned u[2]; unsigned long long ull; } q;
          q.u[0] = pk2(sregs[p][0], sregs[p][1]);
          q.u[1] = pk2(sregs[p][2], sregs[p][3]);
          *reinterpret_cast<unsigned long long*>(&lds[cur ^ 1][byte]) = q.ull;
        }
      }
      __syncthreads();
      cur ^= 1;
    }

    const int m = m0 + myrow;
    if (m < N) {
#pragma unroll
      for (int nt = 0; nt < 5; ++nt)
#pragma unroll
        for (int r = 0; r < 16; ++r) {
          int n = nt * 32 + (r & 3) + 8 * (r >> 2) + 4 * h;
          if (n < 131) k1T[(size_t)n * N + m] = acc[nt][r];
        }
    }
    return;
  }

  // ---- K3: atom MLP over edges, atomic segment sum into agg ----
  const int e = (blockIdx.x - G1) * 128 + w * 32 + ln;
  const bool valid = (e < E);
  const int ec = valid ? e : (E - 1);
  const int row = eidx[ec];
  const int col = eidx[(size_t)E + ec];
  const int typ = etype[ec];
  const float e0 = eattr[2 * (size_t)ec];
  const float e1 = eattr[2 * (size_t)ec + 1];

  const unsigned short* hr = h_bf + (size_t)row * 128 + h * 64;
  const unsigned short* hc = h_bf + (size_t)col * 128 + h * 64;
  const unsigned short* bb = bond_bf + (size_t)typ * 128 + h * 64;

  f32x16 acc[4];
#pragma unroll
  for (int q = 0; q < 4; ++q) acc[q] = zero16();

#pragma unroll
  for (int kc = 0; kc < 8; ++kc) {
    bfrag8 b = ldfrag(hr + kc * 8);
    const unsigned short* wp = W1aT + ((size_t)(kc * 4) * 64 + lane) * 8;
#pragma unroll
    for (int nt = 0; nt < 4; ++nt) acc[nt] = MFMA32(ldfrag(wp + nt * 512), b, acc[nt]);
  }
#pragma unroll
  for (int kc = 0; kc < 8; ++kc) {
    bfrag8 b = ldfrag(hc + kc * 8);
    const unsigned short* wp = W1bT + ((size_t)(kc * 4) * 64 + lane) * 8;
#pragma unroll
    for (int nt = 0; nt < 4; ++nt) acc[nt] = MFMA32(ldfrag(wp + nt * 512), b, acc[nt]);
  }
#pragma unroll
  for (int kc = 0; kc < 8; ++kc) {
    bfrag8 b = ldfrag(bb + kc * 8);
    const unsigned short* wp = W1cT + ((size_t)(kc * 4) * 64 + lane) * 8;
#pragma unroll
    for (int nt = 0; nt < 4; ++nt) acc[nt] = MFMA32(ldfrag(wp + nt * 512), b, acc[nt]);
  }
  {
    unsigned u0 = h ? 0u : pk2(e0, e1);
    unsigned u1 = h ? 0u : 0x00003F80u;  // bf16(1.0) at k=2 -> carries ab1
    bfrag8 b = frag4(u0, u1, 0u, 0u);
    const unsigned short* wp = W1eT + (size_t)lane * 8;
#pragma unroll
    for (int nt = 0; nt < 4; ++nt) acc[nt] = MFMA32(ldfrag(wp + nt * 512), b, acc[nt]);
  }

  unsigned wv[32];
#pragma unroll
  for (int nt = 0; nt < 4; ++nt)
#pragma unroll
    for (int p = 0; p < 8; ++p)
      wv[nt * 8 + p] = pk2(silu_f(acc[nt][2 * p]), silu_f(acc[nt][2 * p + 1]));

#pragma unroll
  for (int q = 0; q < 4; ++q) acc[q] = zero16();
#pragma unroll
  for (int kc = 0; kc < 8; ++kc) {
    const int base = (kc >> 1) * 8 + (kc & 1) * 4;
    unsigned a0 = wv[base + 0], a1 = wv[base + 1], a2 = wv[base + 2], a3 = wv[base + 3];
    unsigned s0 = (unsigned)__shfl_xor((int)a0, 32);
    unsigned s1 = (unsigned)__shfl_xor((int)a1, 32);
    unsigned s2 = (unsigned)__shfl_xor((int)a2, 32);
    unsigned s3 = (unsigned)__shfl_xor((int)a3, 32);
    bfrag8 b = frag4(h ? s2 : a0, h ? s3 : a1, h ? a2 : s0, h ? a3 : s1);
    const unsigned short* wp = W2T + ((size_t)(kc * 4) * 64 + lane) * 8;
#pragma unroll
    for (int nt = 0; nt < 4; ++nt) acc[nt] = MFMA32(ldfrag(wp + nt * 512), b, acc[nt]);
  }

  float part = 0.0f;
#pragma unroll
  for (int nt = 0; nt < 4; ++nt)
#pragma unroll
    for (int r = 0; r < 16; ++r) {
      int n = nt * 32 + (r & 3) + 8 * (r >> 2) + 4 * h;
      part += silu_f(acc[nt][r] + ab2[n]) * aW3[n];
    }
  float mv = part + __shfl_xor(part, 32);

  if (valid) {
    float tt = tanhf(mv) * 0.1f;  // *10 (COORDS_RANGE) / 100 (NORM_FACTOR)
    if (h == 0) {
      atomicAdd(agg + 3 * (size_t)row + 0, cda[3 * (size_t)ec + 0] * tt);
      atomicAdd(agg + 3 * (size_t)row + 1, cda[3 * (size_t)ec + 1] * tt);
    } else {
      atomicAdd(agg + 3 * (size_t)row + 2, cda[3 * (size_t)ec + 2] * tt);
    }
  }
}

// ---------------- K2: fragment MLP + compose output ----------------
__global__ __launch_bounds__(256) void k2_frag(
    const float* __restrict__ x_a, const unsigned short* __restrict__ h_bf,
    const float* __restrict__ k1T, const float* __restrict__ agg,
    const unsigned short* __restrict__ fW1aT, const unsigned short* __restrict__ fW2T,
    const float* __restrict__ fW1, const float* __restrict__ fb1,
    const float* __restrict__ fb2, const float* __restrict__ fW3,
    float* __restrict__ out, int N) {
  const int lane = threadIdx.x & 63;
  const int wid = threadIdx.x >> 6;
  const int h = lane >> 5;
  const int ln = lane & 31;
  const int i = blockIdx.x * 128 + wid * 32 + ln;
  const bool valid = (i < N);
  const int ic = valid ? i : (N - 1);

  float cd[3];
  float radial = 0.0f;
#pragma unroll
  for (int c = 0; c < 3; ++c) {
    float v = x_a[3 * (size_t)ic + c] - k1T[(size_t)(128 + c) * N + ic];
    cd[c] = v;
    radial += v * v;
  }

  f32x16 acc[4];
#pragma unroll
  for (int q = 0; q < 4; ++q) acc[q] = zero16();
  const unsigned short* hp = h_bf + (size_t)ic * 128 + h * 64;
#pragma unroll
  for (int kc = 0; kc < 8; ++kc) {
    bfrag8 b = ldfrag(hp + kc * 8);
    const unsigned short* wp = fW1aT + ((size_t)(kc * 4) * 64 + lane) * 8;
#pragma unroll
    for (int nt = 0; nt < 4; ++nt) acc[nt] = MFMA32(ldfrag(wp + nt * 512), b, acc[nt]);
  }

  unsigned wv[32];
#pragma unroll
  for (int nt = 0; nt < 4; ++nt)
#pragma unroll
    for (int p = 0; p < 8; ++p) {
      const int r0 = 2 * p;
      const int n0 = nt * 32 + (r0 & 3) + 8 * (r0 >> 2) + 4 * h;
      const int n1 = n0 + 1;
      float q0 = acc[nt][r0] + k1T[(size_t)n0 * N + ic]
               + radial * (fW1[(size_t)256 * 128 + n0] + fW1[(size_t)257 * 128 + n0]) + fb1[n0];
      float q1 = acc[nt][r0 + 1] + k1T[(size_t)n1 * N + ic]
               + radial * (fW1[(size_t)256 * 128 + n1] + fW1[(size_t)257 * 128 + n1]) + fb1[n1];
      wv[nt * 8 + p] = pk2(silu_f(q0), silu_f(q1));
    }

#pragma unroll
  for (int q = 0; q < 4; ++q) acc[q] = zero16();
#pragma unroll
  for (int kc = 0; kc < 8; ++kc) {
    const int base = (kc >> 1) * 8 + (kc & 1) * 4;
    unsigned a0 = wv[base + 0], a1 = wv[base + 1], a2 = wv[base + 2], a3 = wv[base + 3];
    unsigned s0 = (unsigned)__shfl_xor((int)a0, 32);
    unsigned s1 = (unsigned)__shfl_xor((int)a1, 32);
    unsigned s2 = (unsigned)__shfl_xor((int)a2, 32);
    unsigned s3 = (unsigned)__shfl_xor((int)a3, 32);
    bfrag8 b = frag4(h ? s2 : a0, h ? s3 : a1, h ? a2 : s0, h ? a3 : s1);
    const unsigned short* wp = fW2T + ((size_t)(kc * 4) * 64 + lane) * 8;
#pragma unroll
    for (int nt = 0; nt < 4; ++nt) acc[nt] = MFMA32(ldfrag(wp + nt * 512), b, acc[nt]);
  }

  float part = 0.0f;
#pragma unroll
  for (int nt = 0; nt < 4; ++nt)
#pragma unroll
    for (int r = 0; r < 16; ++r) {
      int n = nt * 32 + (r & 3) + 8 * (r >> 2) + 4 * h;
      part += silu_f(acc[nt][r] + fb2[n]) * fW3[n];
    }
  float mv = part + __shfl_xor(part, 32);

  if (valid && h == 0) {
    float nrm = sqrtf(radial + 1e-8f);
    float s = tanhf(mv) * 10.0f / (nrm + 1.0f);
#pragma unroll
    for (int c = 0; c < 3; ++c)
      out[3 * (size_t)i + c] = x_a[3 * (size_t)i + c] + cd[c] * s + agg[3 * (size_t)i + c];
  }
}

// ---------------- launch ----------------

extern "C" void kernel_launch(void* const* d_in, const int* in_sizes, int n_in,
                              void* d_out, int out_size, void* d_ws, size_t ws_size,
                              hipStream_t stream) {
  const float* h_a    = (const float*)d_in[0];
  const float* x_a    = (const float*)d_in[1];
  const int*   e_idx  = (const int*)d_in[2];
  const int*   e_type = (const int*)d_in[3];
  const float* e_attr = (const float*)d_in[4];
  const float* cda    = (const float*)d_in[5];
  const float* h_f    = (const float*)d_in[6];
  const float* x_f    = (const float*)d_in[7];
  const float* bm     = (const float*)d_in[8];
  const float* bond   = (const float*)d_in[9];
  const float* aW1    = (const float*)d_in[10];
  const float* ab1    = (const float*)d_in[11];
  const float* aW2    = (const float*)d_in[12];
  const float* ab2    = (const float*)d_in[13];
  const float* aW3    = (const float*)d_in[14];
  const float* fW1    = (const float*)d_in[15];
  const float* fb1    = (const float*)d_in[16];
  const float* fW2    = (const float*)d_in[17];
  const float* fb2    = (const float*)d_in[18];
  const float* fW3    = (const float*)d_in[19];
  float* out = (float*)d_out;

  const int N  = in_sizes[0] / 128;
  const int E  = in_sizes[2] / 2;
  const int F  = in_sizes[6] / 128;
  const int NB = in_sizes[9] / 128;
  const int KC = F / 16;

  char* wsp = (char*)d_ws;
  size_t off = 0;
  auto alloc = [&](size_t bytes) -> char* {
    char* p = wsp + off;
    off += (bytes + 255) & ~(size_t)255;
    return p;
  };
  unsigned short* h_bf    = (unsigned short*)alloc((size_t)N * 128 * 2);
  unsigned short* bond_bf = (unsigned short*)alloc((size_t)NB * 128 * 2);
  float*          hfp     = (float*)alloc((size_t)F * 128 * 4);
  unsigned short* bmT     = (unsigned short*)alloc((size_t)KC * 5 * 64 * 8 * 2);
  unsigned short* W1aT    = (unsigned short*)alloc(8 * 4 * 64 * 8 * 2);
  unsigned short* W1bT    = (unsigned short*)alloc(8 * 4 * 64 * 8 * 2);
  unsigned short* W1cT    = (unsigned short*)alloc(8 * 4 * 64 * 8 * 2);
  unsigned short* W2T     = (unsigned short*)alloc(8 * 4 * 64 * 8 * 2);
  unsigned short* W1eT    = (unsigned short*)alloc(1 * 4 * 64 * 8 * 2);
  unsigned short* fW1aT   = (unsigned short*)alloc(8 * 4 * 64 * 8 * 2);
  unsigned short* fW2T    = (unsigned short*)alloc(8 * 4 * 64 * 8 * 2);
  float*          k1T     = (float*)alloc((size_t)131 * N * 4);
  float*          agg     = (float*)alloc((size_t)N * 3 * 4);

  const int G_A = (N * 16 + 255) >> 8;
  const int G_B = (NB * 16 + 255) >> 8;
  const int G_H = (F + 1) >> 1;
  const int G_P = 6 * 64;
  const int G_E2 = 8;
  const int G_Z = (N * 3 + 1023) >> 10;
  prep_kernel<<<G_A + G_B + G_H + G_P + G_E2 + G_Z, 256, 0, stream>>>(
      h_a, bond, h_f, aW1, ab1, aW2, fW1, fW2,
      h_bf, bond_bf, hfp, W1aT, W1bT, W1cT, W1eT, W2T, fW1aT, fW2T, agg,
      N, NB, F);

  {
    int total = KC * 5 * 64 * 8;
    pack_bmat_kernel<<<(total + 255) / 256, 256, 0, stream>>>(hfp, x_f, bmT, total);
  }

  const int G1 = (N + 127) / 128;
  const int G3 = (E + 127) / 128;
  fused_k1_k3<<<G1 + G3, 256, 0, stream>>>(
      bm, bmT, k1T,
      h_bf, bond_bf, e_idx, e_type, e_attr, cda,
      W1aT, W1bT, W1cT, W1eT, W2T, ab2, aW3, agg,
      N, F, E, G1);

  k2_frag<<<(N + 127) / 128, 256, 0, stream>>>(x_a, h_bf, k1T, agg, fW1aT, fW2T,
                                               fW1, fb1, fb2, fW3, out, N);
}